// Round 15
// baseline (135.391 us; speedup 1.0000x reference)
//
#include <hip/hip_runtime.h>

typedef unsigned short u16;
typedef __attribute__((ext_vector_type(8))) __bf16 bf16x8;
typedef __attribute__((ext_vector_type(4))) float f32x4;
typedef __attribute__((ext_vector_type(4))) u16 u16x4;

// ---------------- helpers ----------------

__device__ __forceinline__ u16 f2bf(float f) {
  unsigned u = __float_as_uint(f);
  u += 0x7fff + ((u >> 16) & 1);   // RNE
  return (u16)(u >> 16);
}

__device__ __forceinline__ f32x4 mfma16(bf16x8 a, bf16x8 b, f32x4 c) {
  return __builtin_amdgcn_mfma_f32_16x16x32_bf16(a, b, c, 0, 0, 0);
}

__device__ __forceinline__ void gload16(const void* g, void* l) {
  __builtin_amdgcn_global_load_lds(
      (__attribute__((address_space(1))) unsigned int*)(const_cast<void*>(g)),
      (__attribute__((address_space(3))) unsigned int*)l, 16, 0, 0);
}

// ---------------- fused prep kernel ----------------
// blocks [0,4096):     x f32 -> bf16 (1048576 float4 chunks)
// blocks [4096,8192):  W transpose+convert, z = (bx-4096)>>10, 32x32 tiles
//                      (vectorized: float4 global loads, u16x4 global stores;
//                       tile[32][33] keeps both LDS phases <=2-way = free)
// blocks [8192,8256):  rel f32 -> bf16
// blocks [8256,8268):  bias pack

__global__ void k_prep_all(const float* __restrict__ x, u16* __restrict__ xb,
                           const float* __restrict__ W0, const float* __restrict__ W1,
                           const float* __restrict__ W2, const float* __restrict__ W3,
                           u16* __restrict__ Wt,
                           const float* __restrict__ rel, u16* __restrict__ relb,
                           const float* __restrict__ bq, const float* __restrict__ bk,
                           const float* __restrict__ bv, float* __restrict__ bias) {
  __shared__ float tile[32][33];
  const int bx = blockIdx.x, t = threadIdx.x;
  if (bx < 4096) {
    int i = bx * 256 + t;
    float4 v = reinterpret_cast<const float4*>(x)[i];
    u16x4 o;
    o.x = f2bf(v.x); o.y = f2bf(v.y); o.z = f2bf(v.z); o.w = f2bf(v.w);
    reinterpret_cast<u16x4*>(xb)[i] = o;
  } else if (bx < 8192) {
    const int id = bx - 4096;
    const int z = id >> 10;
    const float* in = (z == 0) ? W0 : (z == 1) ? W1 : (z == 2) ? W2 : W3;
    u16* out = Wt + (size_t)z * 1024 * 1024;
    const int r0 = ((id >> 5) & 31) * 32, c0 = (id & 31) * 32;
    const int r = t >> 3, c4 = t & 7;     // 256 threads = 32 rows x 8 float4 chunks
    float4 v = *reinterpret_cast<const float4*>(&in[(size_t)(r0 + r) * 1024 + c0 + c4 * 4]);
    tile[r][c4 * 4 + 0] = v.x;
    tile[r][c4 * 4 + 1] = v.y;
    tile[r][c4 * 4 + 2] = v.z;
    tile[r][c4 * 4 + 3] = v.w;
    __syncthreads();
    u16x4 o;
    o.x = f2bf(tile[c4 * 4 + 0][r]);
    o.y = f2bf(tile[c4 * 4 + 1][r]);
    o.z = f2bf(tile[c4 * 4 + 2][r]);
    o.w = f2bf(tile[c4 * 4 + 3][r]);
    *reinterpret_cast<u16x4*>(&out[(size_t)(c0 + r) * 1024 + r0 + c4 * 4]) = o;
  } else if (bx < 8256) {
    int i = (bx - 8192) * 256 + t;
    float4 v = reinterpret_cast<const float4*>(rel)[i];
    u16x4 o;
    o.x = f2bf(v.x); o.y = f2bf(v.y); o.z = f2bf(v.z); o.w = f2bf(v.w);
    reinterpret_cast<u16x4*>(relb)[i] = o;
  } else {
    int i = (bx - 8256) * 256 + t;
    if (i < 3072) bias[i] = (i < 1024) ? bq[i] : (i < 2048 ? bk[i - 1024] : bv[i - 2048]);
  }
}

// ---------------- GEMM: C[m][n] = sum_k A[m][k]*B[n][k] + bias[n] ----------------
// BK=64, 128xBN tile, XOR-16 swizzled LDS rows (staged via pre-swizzled global
// source + linear gload_lds dest; read back with same XOR).
// CONFIG SPACE FULLY MAPPED (r7-r13): {BK 32/64} x {BN 64/128} x {PIPE 0/1}.
//   QKV: BK64/BN128/PIPE0 (BN=64: +9us r10; PIPE=1: +12us r13)
//   Wo:  BK64/BN64/PIPE1  (grid-limited to 2 blocks/CU, so dbuf is free)
// Rule: pipeline only when it costs no residency.
// MODE 0: fp32 output. MODE 2: bf16 output + cols >= 2048 (V block of fused
// QKV GEMM) routed to Vaux transposed: Vaux[(b*1024 + (col-2048))*1024 + s].

template<int MODE, int BN, int PIPE>
__global__ __launch_bounds__(256) void k_gemm(
    const u16* __restrict__ A, const u16* __restrict__ B,
    const float* __restrict__ bias, void* __restrict__ Cout,
    u16* __restrict__ Vaux, int M, int N, int Kd)
{
  constexpr int NF = BN / 32;      // N fragments per wave (4 or 2)
  constexpr int NB = PIPE ? 2 : 1;
  __shared__ u16 Alds[NB][128 * 64];   // 16 KB each, swizzled: byte = row*128 + (cb ^ ((row&7)<<4))
  __shared__ u16 Blds[NB][BN * 64];
  const int t = threadIdx.x;
  const int lane = t & 63, wid = t >> 6;
  const int wr = wid >> 1, wc = wid & 1;
  const int l15 = lane & 15, lg = lane >> 4;
  const int m0 = blockIdx.y * 128, n0 = blockIdx.x * BN;

  const f32x4 fzero = {0.f, 0.f, 0.f, 0.f};
  f32x4 acc[4][NF];
#pragma unroll
  for (int i = 0; i < 4; i++)
#pragma unroll
    for (int j = 0; j < NF; j++) acc[i][j] = fzero;

  // staging: thread t stages A chunks {t+256*ci, ci<4}, B chunks {t+256*ci, ci<NF}.
  // chunk c: row = c>>3 (row&7 is ci-invariant), col byte = (c&7)*16, source col
  // inverse-swizzled so LDS holds the swizzled layout with a linear dest.
  const int srow = t >> 3;                                  // 0..31
  const int scb  = ((t & 7) * 16) ^ ((srow & 7) << 4);      // byte offset in 128B row
  const size_t abase = (size_t)(m0 + srow) * Kd + (scb >> 1);
  const size_t bbase = (size_t)(n0 + srow) * Kd + (scb >> 1);

  auto stage = [&](int buf, int k0) {
#pragma unroll
    for (int ci = 0; ci < 4; ci++)
      gload16(A + abase + (size_t)(32 * ci) * Kd + k0, Alds[buf] + (t + 256 * ci) * 8);
#pragma unroll
    for (int ci = 0; ci < NF; ci++)
      gload16(B + bbase + (size_t)(32 * ci) * Kd + k0, Blds[buf] + (t + 256 * ci) * 8);
  };

  auto compute = [&](int buf) {
#pragma unroll
    for (int kk = 0; kk < 2; kk++) {
      bf16x8 av[4], bv[NF];
#pragma unroll
      for (int mi = 0; mi < 4; mi++) {
        const int row = wr * 64 + mi * 16 + l15;
        av[mi] = *reinterpret_cast<const bf16x8*>(
            (const char*)Alds[buf] + row * 128 + ((kk * 64 + lg * 16) ^ ((row & 7) << 4)));
      }
#pragma unroll
      for (int ni = 0; ni < NF; ni++) {
        const int row = wc * (BN / 2) + ni * 16 + l15;
        bv[ni] = *reinterpret_cast<const bf16x8*>(
            (const char*)Blds[buf] + row * 128 + ((kk * 64 + lg * 16) ^ ((row & 7) << 4)));
      }
#pragma unroll
      for (int mi = 0; mi < 4; mi++)
#pragma unroll
        for (int ni = 0; ni < NF; ni++)
          acc[mi][ni] = mfma16(av[mi], bv[ni], acc[mi][ni]);
    }
  };

  if (PIPE) {
    // 2-phase: one barrier per tile; prefetch in flight across the compute.
    stage(0, 0);
    int cur = 0;
    for (int k0 = 0; k0 < Kd; k0 += 64) {
      __syncthreads();               // drains stage of buf[cur]; all waves past compute of buf[cur^1]
      if (k0 + 64 < Kd) stage(cur ^ 1, k0 + 64);
      compute(cur);
      cur ^= 1;
    }
  } else {
    for (int k0 = 0; k0 < Kd; k0 += 64) {
      stage(0, k0);
      __syncthreads();
      compute(0);
      __syncthreads();
    }
  }

#pragma unroll
  for (int mi = 0; mi < 4; mi++) {
#pragma unroll
    for (int ni = 0; ni < NF; ni++) {
      const int col = n0 + wc * (BN / 2) + ni * 16 + l15;
      const float bcol = bias[col];
#pragma unroll
      for (int r = 0; r < 4; r++) {
        const int row = m0 + wr * 64 + mi * 16 + lg * 4 + r;
        const float v = acc[mi][ni][r] + bcol;
        if (MODE == 0) {
          ((float*)Cout)[(size_t)row * N + col] = v;
        } else {
          if (col < 2048) {
            ((u16*)Cout)[(size_t)row * N + col] = f2bf(v);
          } else {
            const int bb = row >> 10, ss = row & 1023;
            Vaux[((size_t)bb * 1024 + (col - 2048)) * 1024 + ss] = f2bf(v);
          }
        }
      }
    }
  }
}

// ---------------- attention ----------------
// r15: 8-wave / 128-q-row blocks. The per-wave iteration (proven at 60.3 us,
// reproduced 5x: W-band LDS combine, inline rel loads, setprio, single-buffered
// stage->sync->compute) is BYTE-IDENTICAL; the only change is that each staged
// 16KB K/V tile now feeds 8 waves instead of 4, halving per-CU staging count
// (34 -> 18). This is the REVERSE of r5's mistake (smaller blocks doubled
// stagings and lost). Wave count/CU unchanged: 2 blocks x 8 waves = 16.
// LDS = 8K K + 8K V + 8x5376 Sbuf = 59392 B -> 2 blocks/CU.
// qt map {7,5,3,1,0,2,4,6}: round-robin residency pairs (g, g+4) each sum
// nk = 18 (balanced); heavy-first dispatch; bh%8 -> XCD locality preserved.
// Revert criterion: k_attn >= 60 us or fail -> restore r14 verbatim.

__global__ __launch_bounds__(512, 4) void k_attn(
    const u16* __restrict__ qkv,   // (4096, 3072): Q|K|V
    const u16* __restrict__ vt,    // (64*64, 1024): Vt[bh*64+d][s]
    const u16* __restrict__ relb,  // (1024, 64)
    u16* __restrict__ Oout)        // (4096, 1024)
{
  __shared__ u16 Klds[64 * 64];        // 8 KB, swizzled: byte = row*128 + (cb ^ ((row&7)<<4))
  __shared__ u16 Vlds[64 * 64];        // 8 KB, same swizzle (rows = d)
  __shared__ float Sbuf[8][16 * 84];   // 43 KB, per-wave: W band f32 (stride 84); P (bf16) aliases base

  const int t = threadIdx.x;           // 0..511
  const int lane = t & 63, w = t >> 6; // w 0..7
  const int l15 = lane & 15, lg = lane >> 4;
  const int blk = blockIdx.x;          // 0..511
  const int bh = blk & 63;             // blocks of a bh share an XCD (blk%8 == bh%8)
  const int g = blk >> 6;              // 0..7
  // qt map {7,5,3,1,0,2,4,6}: pairs (g,g+4) have nk sums 18; heavy first.
  const int qt = (g < 4) ? (7 - 2 * g) : (2 * (g - 4));
  const int b = bh >> 4, h = bh & 15;
  const int qb = qt * 128;             // 128 q-rows per block
  const int qw = qb + w * 16;

  float* Wb = Sbuf[w];
  u16* Pb = (u16*)Sbuf[w];             // aliases Wb; ordering via wave_barrier fences

  const f32x4 fzero = {0.f, 0.f, 0.f, 0.f};

  // Q A-fragments, held in registers
  const size_t qrow = (size_t)(b * 1024 + qw + l15) * 3072 + h * 64;
  bf16x8 aQ0 = *reinterpret_cast<const bf16x8*>(qkv + qrow + lg * 8);
  bf16x8 aQ1 = *reinterpret_cast<const bf16x8*>(qkv + qrow + 32 + lg * 8);

  f32x4 oacc[4];
  float l_r[4];
#pragma unroll
  for (int r = 0; r < 4; r++) { oacc[r] = fzero; l_r[r] = 0.f; }

  // staging: 512 threads stage 512 16B chunks each for K and V (1 chunk/thread
  // per array). chunk t: row = t>>3 (0..63), col byte = (t&7)*16, source col
  // inverse-swizzled so LDS holds the swizzled layout with a linear dest.
  const int srow = t >> 3;             // 0..63
  const int scb = ((t & 7) * 16) ^ ((srow & 7) << 4);
  const u16* Ks = qkv + (size_t)(b * 1024 + srow) * 3072 + 1024 + h * 64 + (scb >> 1);
  const u16* Vs = vt + (size_t)(bh * 64 + srow) * 1024 + (scb >> 1);
  u16* Kd = Klds + t * 8;
  u16* Vd = Vlds + t * 8;

  const int nk = 2 * qt + 2;           // uniform trip count across the 8 waves
  const float SC = 0.125f * 1.44269504f;   // fold 1/sqrt(D) and log2(e)

  for (int kt = 0; kt < nk; kt++) {
    const int k0 = kt * 64;
    gload16(Ks + (size_t)k0 * 3072, Kd);
    gload16(Vs + k0, Vd);
    __syncthreads();   // drains vmcnt for all waves; K/V tile ready

    // content scores: 16 q x 64 k from swizzled Klds
    __builtin_amdgcn_s_setprio(1);
    f32x4 sc4[4];
#pragma unroll
    for (int tt = 0; tt < 4; tt++) sc4[tt] = fzero;
#pragma unroll
    for (int tt = 0; tt < 4; tt++) {
      const int row = tt * 16 + l15;
      const int sw = (row & 7) << 4;
      bf16x8 b0 = *reinterpret_cast<const bf16x8*>((const char*)Klds + row * 128 + ((lg * 16) ^ sw));
      bf16x8 b1 = *reinterpret_cast<const bf16x8*>((const char*)Klds + row * 128 + ((64 + lg * 16) ^ sw));
      sc4[tt] = mfma16(aQ0, b0, sc4[tt]);
      sc4[tt] = mfma16(aQ1, b1, sc4[tt]);
    }

    // rel band: W[q][j] = Q[q]·rel[rbase+j], j in [0,80); direct global (L2-hot)
    const int rbase = 1008 + k0 - qw;
#pragma unroll
    for (int wj = 0; wj < 5; wj++) {
      int rr = rbase + wj * 16 + l15;
      rr = rr < 0 ? 0 : (rr > 1023 ? 1023 : rr);   // clamped rows feed only masked entries
      const u16* rp = relb + rr * 64;
      bf16x8 b0 = *reinterpret_cast<const bf16x8*>(rp + lg * 8);
      bf16x8 b1 = *reinterpret_cast<const bf16x8*>(rp + 32 + lg * 8);
      f32x4 z = fzero;
      z = mfma16(aQ0, b0, z);
      z = mfma16(aQ1, b1, z);
#pragma unroll
      for (int r = 0; r < 4; r++)
        Wb[(lg * 4 + r) * 84 + wj * 16 + l15] = z[r];
    }
    __builtin_amdgcn_s_setprio(0);
    __builtin_amdgcn_wave_barrier();

    // combine + mask + exp2 (defer-max: static max 0); per-lane l partials
    float pvv[4][4];
#pragma unroll
    for (int r = 0; r < 4; r++) {
      const int rowi = lg * 4 + r;
      const int q = qw + rowi;
      const float* wrow = Wb + rowi * 84 + (15 - rowi);
#pragma unroll
      for (int tt = 0; tt < 4; tt++) {
        const int kg = k0 + tt * 16 + l15;
        float s = (sc4[tt][r] + wrow[tt * 16 + l15]) * SC;
        s = (kg <= q) ? s : -1e30f;
        float p = exp2f(s);
        pvv[tt][r] = p;
        l_r[r] += p;
      }
    }
    __builtin_amdgcn_wave_barrier();
    asm volatile("" ::: "memory");     // order W-reads before aliased P-writes

    // P -> LDS bf16, swizzled rows of 128B
#pragma unroll
    for (int tt = 0; tt < 4; tt++)
#pragma unroll
      for (int r = 0; r < 4; r++) {
        const int rowi = lg * 4 + r;
        const int cb = (32 * tt + 2 * l15) ^ ((rowi & 7) << 4);
        *(u16*)((char*)Pb + rowi * 128 + cb) = f2bf(pvv[tt][r]);
      }
    __builtin_amdgcn_wave_barrier();

    // PV from swizzled Plds (A) and Vlds (B)
    __builtin_amdgcn_s_setprio(1);
#pragma unroll
    for (int s = 0; s < 2; s++) {
      const int acb = (s * 64 + lg * 16) ^ ((l15 & 7) << 4);
      bf16x8 aP = *reinterpret_cast<const bf16x8*>((const char*)Pb + l15 * 128 + acb);
#pragma unroll
      for (int dt = 0; dt < 4; dt++) {
        const int vrow = dt * 16 + l15;
        const int vcb = (s * 64 + lg * 16) ^ ((vrow & 7) << 4);
        bf16x8 bV = *reinterpret_cast<const bf16x8*>((const char*)Vlds + vrow * 128 + vcb);
        oacc[dt] = mfma16(aP, bV, oacc[dt]);
      }
    }
    __builtin_amdgcn_s_setprio(0);
    __syncthreads();   // all waves done with K/V/P before restaging
  }

  // epilogue: one row-sum reduce, scale, store
#pragma unroll
  for (int r = 0; r < 4; r++) {
    float l = l_r[r];
#pragma unroll
    for (int xm = 1; xm < 16; xm <<= 1) l += __shfl_xor(l, xm);
    const float inv = 1.f / l;
    const int q = qw + lg * 4 + r;
#pragma unroll
    for (int dt = 0; dt < 4; dt++)
      Oout[(size_t)(b * 1024 + q) * 1024 + h * 64 + dt * 16 + l15] = f2bf(oacc[dt][r] * inv);
  }
}

// ---------------- launcher ----------------

extern "C" void kernel_launch(void* const* d_in, const int* in_sizes, int n_in,
                              void* d_out, int out_size, void* d_ws, size_t ws_size,
                              hipStream_t stream) {
  const float* x   = (const float*)d_in[0];
  const float* Wq  = (const float*)d_in[1];
  const float* bq  = (const float*)d_in[2];
  const float* Wk  = (const float*)d_in[3];
  const float* bk  = (const float*)d_in[4];
  const float* Wv  = (const float*)d_in[5];
  const float* bv  = (const float*)d_in[6];
  const float* Wo  = (const float*)d_in[7];
  const float* bo  = (const float*)d_in[8];
  const float* rel = (const float*)d_in[9];

  const size_t MB = 1024 * 1024;
  char* ws = (char*)d_ws;
  u16*   xb    = (u16*)(ws);                 // 8MB; reused for attn O after QKV GEMM
  u16*   Wt    = (u16*)(ws + 8 * MB);        // 4096x1024 bf16 (Wq^T|Wk^T|Wv^T|Wo^T)
  u16*   qkvb  = (u16*)(ws + 16 * MB);       // 4096x3072 bf16 (V region unused)
  u16*   vtb   = (u16*)(ws + 40 * MB);       // 4096x1024 bf16 (transposed V)
  u16*   relbb = (u16*)(ws + 48 * MB);       // 1024x64 bf16
  float* bqkv  = (float*)(ws + 49 * MB);     // 3072 f32
  u16*   Ob    = xb;

  // 1) all conversions/packs/transposes in ONE launch (W-transpose vectorized)
  k_prep_all<<<8268, 256, 0, stream>>>(x, xb, Wq, Wk, Wv, Wo, Wt, rel, relbb, bq, bk, bv, bqkv);

  // 2) fused QKV projection (BK=64, BN=128, PIPE=0 -- proven optimum);
  //    V block written transposed into vtb
  k_gemm<2, 128, 0><<<dim3(24, 32), 256, 0, stream>>>(xb, Wt, bqkv, qkvb, vtb, 4096, 3072, 1024);

  // 3) attention: 512 blocks x 8 waves (128 q-rows/block) -- halved staging
  //    count, per-wave iteration identical to the proven 60.3us kernel
  k_attn<<<512, 512, 0, stream>>>(qkvb, vtb, relbb, Ob);

  // 4) output projection (BK=64, BN=64, PIPE=1 -- grid-limited so dbuf is free)
  k_gemm<0, 64, 1><<<dim3(16, 32), 256, 0, stream>>>(Ob, Wt + 3 * MB, bo, d_out, nullptr, 4096, 1024, 1024);
}

// Round 16
// 125.944 us; speedup vs baseline: 1.0750x; 1.0750x over previous
//
#include <hip/hip_runtime.h>

typedef unsigned short u16;
typedef __attribute__((ext_vector_type(8))) __bf16 bf16x8;
typedef __attribute__((ext_vector_type(4))) float f32x4;
typedef __attribute__((ext_vector_type(4))) u16 u16x4;

// ---------------- helpers ----------------

__device__ __forceinline__ u16 f2bf(float f) {
  unsigned u = __float_as_uint(f);
  u += 0x7fff + ((u >> 16) & 1);   // RNE
  return (u16)(u >> 16);
}

__device__ __forceinline__ f32x4 mfma16(bf16x8 a, bf16x8 b, f32x4 c) {
  return __builtin_amdgcn_mfma_f32_16x16x32_bf16(a, b, c, 0, 0, 0);
}

__device__ __forceinline__ void gload16(const void* g, void* l) {
  __builtin_amdgcn_global_load_lds(
      (__attribute__((address_space(1))) unsigned int*)(const_cast<void*>(g)),
      (__attribute__((address_space(3))) unsigned int*)l, 16, 0, 0);
}

// ---------------- fused prep kernel ----------------
// blocks [0,4096):     x f32 -> bf16 (1048576 float4 chunks)
// blocks [4096,8192):  W transpose+convert, z = (bx-4096)>>10, 32x32 tiles
//                      (vectorized: float4 global loads, u16x4 global stores;
//                       tile[32][33] keeps both LDS phases <=2-way = free)
// blocks [8192,8256):  rel f32 -> bf16
// blocks [8256,8268):  bias pack

__global__ void k_prep_all(const float* __restrict__ x, u16* __restrict__ xb,
                           const float* __restrict__ W0, const float* __restrict__ W1,
                           const float* __restrict__ W2, const float* __restrict__ W3,
                           u16* __restrict__ Wt,
                           const float* __restrict__ rel, u16* __restrict__ relb,
                           const float* __restrict__ bq, const float* __restrict__ bk,
                           const float* __restrict__ bv, float* __restrict__ bias) {
  __shared__ float tile[32][33];
  const int bx = blockIdx.x, t = threadIdx.x;
  if (bx < 4096) {
    int i = bx * 256 + t;
    float4 v = reinterpret_cast<const float4*>(x)[i];
    u16x4 o;
    o.x = f2bf(v.x); o.y = f2bf(v.y); o.z = f2bf(v.z); o.w = f2bf(v.w);
    reinterpret_cast<u16x4*>(xb)[i] = o;
  } else if (bx < 8192) {
    const int id = bx - 4096;
    const int z = id >> 10;
    const float* in = (z == 0) ? W0 : (z == 1) ? W1 : (z == 2) ? W2 : W3;
    u16* out = Wt + (size_t)z * 1024 * 1024;
    const int r0 = ((id >> 5) & 31) * 32, c0 = (id & 31) * 32;
    const int r = t >> 3, c4 = t & 7;     // 256 threads = 32 rows x 8 float4 chunks
    float4 v = *reinterpret_cast<const float4*>(&in[(size_t)(r0 + r) * 1024 + c0 + c4 * 4]);
    tile[r][c4 * 4 + 0] = v.x;
    tile[r][c4 * 4 + 1] = v.y;
    tile[r][c4 * 4 + 2] = v.z;
    tile[r][c4 * 4 + 3] = v.w;
    __syncthreads();
    u16x4 o;
    o.x = f2bf(tile[c4 * 4 + 0][r]);
    o.y = f2bf(tile[c4 * 4 + 1][r]);
    o.z = f2bf(tile[c4 * 4 + 2][r]);
    o.w = f2bf(tile[c4 * 4 + 3][r]);
    *reinterpret_cast<u16x4*>(&out[(size_t)(c0 + r) * 1024 + r0 + c4 * 4]) = o;
  } else if (bx < 8256) {
    int i = (bx - 8192) * 256 + t;
    float4 v = reinterpret_cast<const float4*>(rel)[i];
    u16x4 o;
    o.x = f2bf(v.x); o.y = f2bf(v.y); o.z = f2bf(v.z); o.w = f2bf(v.w);
    reinterpret_cast<u16x4*>(relb)[i] = o;
  } else {
    int i = (bx - 8256) * 256 + t;
    if (i < 3072) bias[i] = (i < 1024) ? bq[i] : (i < 2048 ? bk[i - 1024] : bv[i - 2048]);
  }
}

// ---------------- GEMM: C[m][n] = sum_k A[m][k]*B[n][k] + bias[n] ----------------
// BK=64, 128xBN tile, XOR-16 swizzled LDS rows (staged via pre-swizzled global
// source + linear gload_lds dest; read back with same XOR).
// CONFIG SPACE FULLY MAPPED (r7-r13): {BK 32/64} x {BN 64/128} x {PIPE 0/1}.
//   QKV: BK64/BN128/PIPE0 (BN=64: +9us r10; PIPE=1: +12us r13 -- costs a
//        resident block AND removes the barrier that let other blocks overlap)
//   Wo:  BK64/BN64/PIPE1  (BN=64: -7.8us r8; PIPE=1: ~-1us r12 -- free, since
//        Wo is grid-limited to 2 blocks/CU either way)
// Rule: pipeline only when it costs no residency.
// MODE 0: fp32 output. MODE 2: bf16 output + cols >= 2048 (V block of fused
// QKV GEMM) routed to Vaux transposed: Vaux[(b*1024 + (col-2048))*1024 + s].

template<int MODE, int BN, int PIPE>
__global__ __launch_bounds__(256) void k_gemm(
    const u16* __restrict__ A, const u16* __restrict__ B,
    const float* __restrict__ bias, void* __restrict__ Cout,
    u16* __restrict__ Vaux, int M, int N, int Kd)
{
  constexpr int NF = BN / 32;      // N fragments per wave (4 or 2)
  constexpr int NB = PIPE ? 2 : 1;
  __shared__ u16 Alds[NB][128 * 64];   // 16 KB each, swizzled: byte = row*128 + (cb ^ ((row&7)<<4))
  __shared__ u16 Blds[NB][BN * 64];
  const int t = threadIdx.x;
  const int lane = t & 63, wid = t >> 6;
  const int wr = wid >> 1, wc = wid & 1;
  const int l15 = lane & 15, lg = lane >> 4;
  const int m0 = blockIdx.y * 128, n0 = blockIdx.x * BN;

  const f32x4 fzero = {0.f, 0.f, 0.f, 0.f};
  f32x4 acc[4][NF];
#pragma unroll
  for (int i = 0; i < 4; i++)
#pragma unroll
    for (int j = 0; j < NF; j++) acc[i][j] = fzero;

  // staging: thread t stages A chunks {t+256*ci, ci<4}, B chunks {t+256*ci, ci<NF}.
  // chunk c: row = c>>3 (row&7 is ci-invariant), col byte = (c&7)*16, source col
  // inverse-swizzled so LDS holds the swizzled layout with a linear dest.
  const int srow = t >> 3;                                  // 0..31
  const int scb  = ((t & 7) * 16) ^ ((srow & 7) << 4);      // byte offset in 128B row
  const size_t abase = (size_t)(m0 + srow) * Kd + (scb >> 1);
  const size_t bbase = (size_t)(n0 + srow) * Kd + (scb >> 1);

  auto stage = [&](int buf, int k0) {
#pragma unroll
    for (int ci = 0; ci < 4; ci++)
      gload16(A + abase + (size_t)(32 * ci) * Kd + k0, Alds[buf] + (t + 256 * ci) * 8);
#pragma unroll
    for (int ci = 0; ci < NF; ci++)
      gload16(B + bbase + (size_t)(32 * ci) * Kd + k0, Blds[buf] + (t + 256 * ci) * 8);
  };

  auto compute = [&](int buf) {
#pragma unroll
    for (int kk = 0; kk < 2; kk++) {
      bf16x8 av[4], bv[NF];
#pragma unroll
      for (int mi = 0; mi < 4; mi++) {
        const int row = wr * 64 + mi * 16 + l15;
        av[mi] = *reinterpret_cast<const bf16x8*>(
            (const char*)Alds[buf] + row * 128 + ((kk * 64 + lg * 16) ^ ((row & 7) << 4)));
      }
#pragma unroll
      for (int ni = 0; ni < NF; ni++) {
        const int row = wc * (BN / 2) + ni * 16 + l15;
        bv[ni] = *reinterpret_cast<const bf16x8*>(
            (const char*)Blds[buf] + row * 128 + ((kk * 64 + lg * 16) ^ ((row & 7) << 4)));
      }
#pragma unroll
      for (int mi = 0; mi < 4; mi++)
#pragma unroll
        for (int ni = 0; ni < NF; ni++)
          acc[mi][ni] = mfma16(av[mi], bv[ni], acc[mi][ni]);
    }
  };

  if (PIPE) {
    // 2-phase: one barrier per tile; prefetch in flight across the compute.
    stage(0, 0);
    int cur = 0;
    for (int k0 = 0; k0 < Kd; k0 += 64) {
      __syncthreads();               // drains stage of buf[cur]; all waves past compute of buf[cur^1]
      if (k0 + 64 < Kd) stage(cur ^ 1, k0 + 64);
      compute(cur);
      cur ^= 1;
    }
  } else {
    for (int k0 = 0; k0 < Kd; k0 += 64) {
      stage(0, k0);
      __syncthreads();
      compute(0);
      __syncthreads();
    }
  }

#pragma unroll
  for (int mi = 0; mi < 4; mi++) {
#pragma unroll
    for (int ni = 0; ni < NF; ni++) {
      const int col = n0 + wc * (BN / 2) + ni * 16 + l15;
      const float bcol = bias[col];
#pragma unroll
      for (int r = 0; r < 4; r++) {
        const int row = m0 + wr * 64 + mi * 16 + lg * 4 + r;
        const float v = acc[mi][ni][r] + bcol;
        if (MODE == 0) {
          ((float*)Cout)[(size_t)row * N + col] = v;
        } else {
          if (col < 2048) {
            ((u16*)Cout)[(size_t)row * N + col] = f2bf(v);
          } else {
            const int bb = row >> 10, ss = row & 1023;
            Vaux[((size_t)bb * 1024 + (col - 2048)) * 1024 + ss] = f2bf(v);
          }
        }
      }
    }
  }
}

// ---------------- attention ----------------
// FINAL: round-3/7 structure + r10 setprio (60.3 us, reproduced 6x; VGPR 60,
// FETCH 12.84MB, conflicts 1.114M). Optimum bracketed on every axis:
//  - rel combine x load placement: inline+W-band unique optimum (4 cells lose
//    10-54us: shuffle combine r1/2/5/6, hoisted loads r2/r8)
//  - block shape: 2-wave=109us (r5), 4-wave=60us, 8-wave=70us (r15 -- barrier
//    width penalty: sync waits on slowest of N waves' serial rel chains)
//  - pipelining: single-buffered optimal (r1/r4 dbuf variants 93-118us)
//  - setprio: -3.6us (r10)
// Cost law: dur ~= stagings/CU x (drain + sync-width(waves/barrier)).
// DO NOT restructure.

__global__ __launch_bounds__(256, 4) void k_attn(
    const u16* __restrict__ qkv,   // (4096, 3072): Q|K|V
    const u16* __restrict__ vt,    // (64*64, 1024): Vt[bh*64+d][s]
    const u16* __restrict__ relb,  // (1024, 64)
    u16* __restrict__ Oout)        // (4096, 1024)
{
  __shared__ u16 Klds[64 * 64];        // 8 KB, swizzled: byte = row*128 + (cb ^ ((row&7)<<4))
  __shared__ u16 Vlds[64 * 64];        // 8 KB, same swizzle (rows = d)
  __shared__ float Sbuf[4][16 * 84];   // 21 KB, per-wave: W band f32 (stride 84); P (bf16) aliases base

  const int t = threadIdx.x;
  const int lane = t & 63, w = t >> 6;
  const int l15 = lane & 15, lg = lane >> 4;
  const int blk = blockIdx.x;
  const int bh = blk & 63;             // blocks of a bh share an XCD (blk%8 == bh%8)
  // balanced q-tile mapping: groups {g, g+4, g+8, g+12} co-reside on one CU;
  // qbt per quarter j: {15-r, 8+r, 7-r, r} -> per-CU sum(nk) == 34 for all r.
  const int g = blk >> 6;
  const int jq = g >> 2, rq = g & 3;
  const int qbt = (jq == 0) ? (15 - rq) : (jq == 1) ? (8 + rq) : (jq == 2) ? (7 - rq) : rq;
  const int b = bh >> 4, h = bh & 15;
  const int qb = qbt * 64;
  const int qw = qb + w * 16;

  float* Wb = Sbuf[w];
  u16* Pb = (u16*)Sbuf[w];             // aliases Wb; ordering via wave_barrier fences

  const f32x4 fzero = {0.f, 0.f, 0.f, 0.f};

  // Q A-fragments, held in registers
  const size_t qrow = (size_t)(b * 1024 + qw + l15) * 3072 + h * 64;
  bf16x8 aQ0 = *reinterpret_cast<const bf16x8*>(qkv + qrow + lg * 8);
  bf16x8 aQ1 = *reinterpret_cast<const bf16x8*>(qkv + qrow + 32 + lg * 8);

  f32x4 oacc[4];
  float l_r[4];
#pragma unroll
  for (int r = 0; r < 4; r++) { oacc[r] = fzero; l_r[r] = 0.f; }

  // staging: thread t stages chunks t and t+256 (16B each) for K and V.
  // dest byte t*16 -> logical (row = t>>3, cb = (t&7)*16); source col byte is
  // inverse-swizzled so LDS holds the swizzled layout with a linear dest.
  const int srow = t >> 3;
  const int scb = ((t & 7) * 16) ^ ((srow & 7) << 4);
  const u16* Ks0 = qkv + (size_t)(b * 1024 + srow) * 3072 + 1024 + h * 64 + (scb >> 1);
  const u16* Ks1 = Ks0 + 32 * 3072;
  const u16* Vs0 = vt + (size_t)(bh * 64 + srow) * 1024 + (scb >> 1);
  const u16* Vs1 = Vs0 + 32 * 1024;
  u16* Kd0 = Klds + t * 8;  u16* Kd1 = Klds + (t + 256) * 8;
  u16* Vd0 = Vlds + t * 8;  u16* Vd1 = Vlds + (t + 256) * 8;

  const int nk = qbt + 1;              // uniform trip count across the 4 waves
  const float SC = 0.125f * 1.44269504f;   // fold 1/sqrt(D) and log2(e)

  for (int kt = 0; kt < nk; kt++) {
    const int k0 = kt * 64;
    gload16(Ks0 + (size_t)k0 * 3072, Kd0);
    gload16(Ks1 + (size_t)k0 * 3072, Kd1);
    gload16(Vs0 + k0, Vd0);
    gload16(Vs1 + k0, Vd1);
    __syncthreads();   // drains vmcnt for all waves; K/V tile ready

    // content scores: 16 q x 64 k from swizzled Klds
    __builtin_amdgcn_s_setprio(1);
    f32x4 sc4[4];
#pragma unroll
    for (int tt = 0; tt < 4; tt++) sc4[tt] = fzero;
#pragma unroll
    for (int tt = 0; tt < 4; tt++) {
      const int row = tt * 16 + l15;
      const int sw = (row & 7) << 4;
      bf16x8 b0 = *reinterpret_cast<const bf16x8*>((const char*)Klds + row * 128 + ((lg * 16) ^ sw));
      bf16x8 b1 = *reinterpret_cast<const bf16x8*>((const char*)Klds + row * 128 + ((64 + lg * 16) ^ sw));
      sc4[tt] = mfma16(aQ0, b0, sc4[tt]);
      sc4[tt] = mfma16(aQ1, b1, sc4[tt]);
    }

    // rel band: W[q][j] = Q[q]·rel[rbase+j], j in [0,80); direct global (L2-hot)
    const int rbase = 1008 + k0 - qw;
#pragma unroll
    for (int wj = 0; wj < 5; wj++) {
      int rr = rbase + wj * 16 + l15;
      rr = rr < 0 ? 0 : (rr > 1023 ? 1023 : rr);   // clamped rows feed only masked entries
      const u16* rp = relb + rr * 64;
      bf16x8 b0 = *reinterpret_cast<const bf16x8*>(rp + lg * 8);
      bf16x8 b1 = *reinterpret_cast<const bf16x8*>(rp + 32 + lg * 8);
      f32x4 z = fzero;
      z = mfma16(aQ0, b0, z);
      z = mfma16(aQ1, b1, z);
#pragma unroll
      for (int r = 0; r < 4; r++)
        Wb[(lg * 4 + r) * 84 + wj * 16 + l15] = z[r];
    }
    __builtin_amdgcn_s_setprio(0);
    __builtin_amdgcn_wave_barrier();

    // combine + mask + exp2 (defer-max: static max 0); per-lane l partials
    float pvv[4][4];
#pragma unroll
    for (int r = 0; r < 4; r++) {
      const int rowi = lg * 4 + r;
      const int q = qw + rowi;
      const float* wrow = Wb + rowi * 84 + (15 - rowi);
#pragma unroll
      for (int tt = 0; tt < 4; tt++) {
        const int kg = k0 + tt * 16 + l15;
        float s = (sc4[tt][r] + wrow[tt * 16 + l15]) * SC;
        s = (kg <= q) ? s : -1e30f;
        float p = exp2f(s);
        pvv[tt][r] = p;
        l_r[r] += p;
      }
    }
    __builtin_amdgcn_wave_barrier();
    asm volatile("" ::: "memory");     // order W-reads before aliased P-writes

    // P -> LDS bf16, swizzled rows of 128B
#pragma unroll
    for (int tt = 0; tt < 4; tt++)
#pragma unroll
      for (int r = 0; r < 4; r++) {
        const int rowi = lg * 4 + r;
        const int cb = (32 * tt + 2 * l15) ^ ((rowi & 7) << 4);
        *(u16*)((char*)Pb + rowi * 128 + cb) = f2bf(pvv[tt][r]);
      }
    __builtin_amdgcn_wave_barrier();

    // PV from swizzled Plds (A) and Vlds (B)
    __builtin_amdgcn_s_setprio(1);
#pragma unroll
    for (int s = 0; s < 2; s++) {
      const int acb = (s * 64 + lg * 16) ^ ((l15 & 7) << 4);
      bf16x8 aP = *reinterpret_cast<const bf16x8*>((const char*)Pb + l15 * 128 + acb);
#pragma unroll
      for (int dt = 0; dt < 4; dt++) {
        const int vrow = dt * 16 + l15;
        const int vcb = (s * 64 + lg * 16) ^ ((vrow & 7) << 4);
        bf16x8 bV = *reinterpret_cast<const bf16x8*>((const char*)Vlds + vrow * 128 + vcb);
        oacc[dt] = mfma16(aP, bV, oacc[dt]);
      }
    }
    __builtin_amdgcn_s_setprio(0);
    __syncthreads();   // all waves done with K/V/P before restaging
  }

  // epilogue: one row-sum reduce, scale, store
#pragma unroll
  for (int r = 0; r < 4; r++) {
    float l = l_r[r];
#pragma unroll
    for (int xm = 1; xm < 16; xm <<= 1) l += __shfl_xor(l, xm);
    const float inv = 1.f / l;
    const int q = qw + lg * 4 + r;
#pragma unroll
    for (int dt = 0; dt < 4; dt++)
      Oout[(size_t)(b * 1024 + q) * 1024 + h * 64 + dt * 16 + l15] = f2bf(oacc[dt][r] * inv);
  }
}

// ---------------- launcher ----------------

extern "C" void kernel_launch(void* const* d_in, const int* in_sizes, int n_in,
                              void* d_out, int out_size, void* d_ws, size_t ws_size,
                              hipStream_t stream) {
  const float* x   = (const float*)d_in[0];
  const float* Wq  = (const float*)d_in[1];
  const float* bq  = (const float*)d_in[2];
  const float* Wk  = (const float*)d_in[3];
  const float* bk  = (const float*)d_in[4];
  const float* Wv  = (const float*)d_in[5];
  const float* bv  = (const float*)d_in[6];
  const float* Wo  = (const float*)d_in[7];
  const float* bo  = (const float*)d_in[8];
  const float* rel = (const float*)d_in[9];

  const size_t MB = 1024 * 1024;
  char* ws = (char*)d_ws;
  u16*   xb    = (u16*)(ws);                 // 8MB; reused for attn O after QKV GEMM
  u16*   Wt    = (u16*)(ws + 8 * MB);        // 4096x1024 bf16 (Wq^T|Wk^T|Wv^T|Wo^T)
  u16*   qkvb  = (u16*)(ws + 16 * MB);       // 4096x3072 bf16 (V region unused)
  u16*   vtb   = (u16*)(ws + 40 * MB);       // 4096x1024 bf16 (transposed V)
  u16*   relbb = (u16*)(ws + 48 * MB);       // 1024x64 bf16
  float* bqkv  = (float*)(ws + 49 * MB);     // 3072 f32
  u16*   Ob    = xb;

  // 1) all conversions/packs/transposes in ONE launch (W-transpose vectorized)
  k_prep_all<<<8268, 256, 0, stream>>>(x, xb, Wq, Wk, Wv, Wo, Wt, rel, relbb, bq, bk, bv, bqkv);

  // 2) fused QKV projection (BK=64, BN=128, PIPE=0 -- proven optimum);
  //    V block written transposed into vtb
  k_gemm<2, 128, 0><<<dim3(24, 32), 256, 0, stream>>>(xb, Wt, bqkv, qkvb, vtb, 4096, 3072, 1024);

  // 3) attention: proven kernel (60.3 us) -- final
  k_attn<<<1024, 256, 0, stream>>>(qkvb, vtb, relbb, Ob);

  // 4) output projection (BK=64, BN=64, PIPE=1 -- grid-limited so dbuf is free)
  k_gemm<0, 64, 1><<<dim3(16, 32), 256, 0, stream>>>(Ob, Wt + 3 * MB, bo, d_out, nullptr, 4096, 1024, 1024);
}

// Round 17
// 124.442 us; speedup vs baseline: 1.0880x; 1.0121x over previous
//
#include <hip/hip_runtime.h>

typedef unsigned short u16;
typedef __attribute__((ext_vector_type(8))) __bf16 bf16x8;
typedef __attribute__((ext_vector_type(4))) float f32x4;
typedef __attribute__((ext_vector_type(4))) u16 u16x4;

// ---------------- helpers ----------------

__device__ __forceinline__ u16 f2bf(float f) {
  unsigned u = __float_as_uint(f);
  u += 0x7fff + ((u >> 16) & 1);   // RNE
  return (u16)(u >> 16);
}

__device__ __forceinline__ f32x4 mfma16(bf16x8 a, bf16x8 b, f32x4 c) {
  return __builtin_amdgcn_mfma_f32_16x16x32_bf16(a, b, c, 0, 0, 0);
}

__device__ __forceinline__ void gload16(const void* g, void* l) {
  __builtin_amdgcn_global_load_lds(
      (__attribute__((address_space(1))) unsigned int*)(const_cast<void*>(g)),
      (__attribute__((address_space(3))) unsigned int*)l, 16, 0, 0);
}

// ---------------- fused prep kernel ----------------
// blocks [0,4096):     x f32 -> bf16 (1048576 float4 chunks)
// blocks [4096,8192):  W transpose+convert, z = (bx-4096)>>10, 32x32 tiles
//                      (vectorized: float4 global loads, u16x4 global stores;
//                       tile[32][33] keeps both LDS phases <=2-way = free)
// blocks [8192,8256):  rel f32 -> bf16
// blocks [8256,8268):  bias pack

__global__ void k_prep_all(const float* __restrict__ x, u16* __restrict__ xb,
                           const float* __restrict__ W0, const float* __restrict__ W1,
                           const float* __restrict__ W2, const float* __restrict__ W3,
                           u16* __restrict__ Wt,
                           const float* __restrict__ rel, u16* __restrict__ relb,
                           const float* __restrict__ bq, const float* __restrict__ bk,
                           const float* __restrict__ bv, float* __restrict__ bias) {
  __shared__ float tile[32][33];
  const int bx = blockIdx.x, t = threadIdx.x;
  if (bx < 4096) {
    int i = bx * 256 + t;
    float4 v = reinterpret_cast<const float4*>(x)[i];
    u16x4 o;
    o.x = f2bf(v.x); o.y = f2bf(v.y); o.z = f2bf(v.z); o.w = f2bf(v.w);
    reinterpret_cast<u16x4*>(xb)[i] = o;
  } else if (bx < 8192) {
    const int id = bx - 4096;
    const int z = id >> 10;
    const float* in = (z == 0) ? W0 : (z == 1) ? W1 : (z == 2) ? W2 : W3;
    u16* out = Wt + (size_t)z * 1024 * 1024;
    const int r0 = ((id >> 5) & 31) * 32, c0 = (id & 31) * 32;
    const int r = t >> 3, c4 = t & 7;     // 256 threads = 32 rows x 8 float4 chunks
    float4 v = *reinterpret_cast<const float4*>(&in[(size_t)(r0 + r) * 1024 + c0 + c4 * 4]);
    tile[r][c4 * 4 + 0] = v.x;
    tile[r][c4 * 4 + 1] = v.y;
    tile[r][c4 * 4 + 2] = v.z;
    tile[r][c4 * 4 + 3] = v.w;
    __syncthreads();
    u16x4 o;
    o.x = f2bf(tile[c4 * 4 + 0][r]);
    o.y = f2bf(tile[c4 * 4 + 1][r]);
    o.z = f2bf(tile[c4 * 4 + 2][r]);
    o.w = f2bf(tile[c4 * 4 + 3][r]);
    *reinterpret_cast<u16x4*>(&out[(size_t)(c0 + r) * 1024 + r0 + c4 * 4]) = o;
  } else if (bx < 8256) {
    int i = (bx - 8192) * 256 + t;
    float4 v = reinterpret_cast<const float4*>(rel)[i];
    u16x4 o;
    o.x = f2bf(v.x); o.y = f2bf(v.y); o.z = f2bf(v.z); o.w = f2bf(v.w);
    reinterpret_cast<u16x4*>(relb)[i] = o;
  } else {
    int i = (bx - 8256) * 256 + t;
    if (i < 3072) bias[i] = (i < 1024) ? bq[i] : (i < 2048 ? bk[i - 1024] : bv[i - 2048]);
  }
}

// ---------------- GEMM: C[m][n] = sum_k A[m][k]*B[n][k] + bias[n] ----------------
// BK=64, 128xBN tile, XOR-16 swizzled LDS rows (staged via pre-swizzled global
// source + linear gload_lds dest; read back with same XOR).
// CONFIG SPACE FULLY MAPPED (r7-r13): {BK 32/64} x {BN 64/128} x {PIPE 0/1}.
//   QKV: BK64/BN128/PIPE0 (BN=64: +9us r10; PIPE=1: +12us r13)
//   Wo:  BK64/BN64/PIPE1  (grid-limited to 2 blocks/CU, so dbuf is free)
// Rule: pipeline only when it costs no residency.
// MODE 0: fp32 output. MODE 2: bf16 output + cols >= 2048 (V block of fused
// QKV GEMM) routed to Vaux transposed: Vaux[(b*1024 + (col-2048))*1024 + s].

template<int MODE, int BN, int PIPE>
__global__ __launch_bounds__(256) void k_gemm(
    const u16* __restrict__ A, const u16* __restrict__ B,
    const float* __restrict__ bias, void* __restrict__ Cout,
    u16* __restrict__ Vaux, int M, int N, int Kd)
{
  constexpr int NF = BN / 32;      // N fragments per wave (4 or 2)
  constexpr int NB = PIPE ? 2 : 1;
  __shared__ u16 Alds[NB][128 * 64];   // 16 KB each, swizzled: byte = row*128 + (cb ^ ((row&7)<<4))
  __shared__ u16 Blds[NB][BN * 64];
  const int t = threadIdx.x;
  const int lane = t & 63, wid = t >> 6;
  const int wr = wid >> 1, wc = wid & 1;
  const int l15 = lane & 15, lg = lane >> 4;
  const int m0 = blockIdx.y * 128, n0 = blockIdx.x * BN;

  const f32x4 fzero = {0.f, 0.f, 0.f, 0.f};
  f32x4 acc[4][NF];
#pragma unroll
  for (int i = 0; i < 4; i++)
#pragma unroll
    for (int j = 0; j < NF; j++) acc[i][j] = fzero;

  // staging: thread t stages A chunks {t+256*ci, ci<4}, B chunks {t+256*ci, ci<NF}.
  // chunk c: row = c>>3 (row&7 is ci-invariant), col byte = (c&7)*16, source col
  // inverse-swizzled so LDS holds the swizzled layout with a linear dest.
  const int srow = t >> 3;                                  // 0..31
  const int scb  = ((t & 7) * 16) ^ ((srow & 7) << 4);      // byte offset in 128B row
  const size_t abase = (size_t)(m0 + srow) * Kd + (scb >> 1);
  const size_t bbase = (size_t)(n0 + srow) * Kd + (scb >> 1);

  auto stage = [&](int buf, int k0) {
#pragma unroll
    for (int ci = 0; ci < 4; ci++)
      gload16(A + abase + (size_t)(32 * ci) * Kd + k0, Alds[buf] + (t + 256 * ci) * 8);
#pragma unroll
    for (int ci = 0; ci < NF; ci++)
      gload16(B + bbase + (size_t)(32 * ci) * Kd + k0, Blds[buf] + (t + 256 * ci) * 8);
  };

  auto compute = [&](int buf) {
#pragma unroll
    for (int kk = 0; kk < 2; kk++) {
      bf16x8 av[4], bv[NF];
#pragma unroll
      for (int mi = 0; mi < 4; mi++) {
        const int row = wr * 64 + mi * 16 + l15;
        av[mi] = *reinterpret_cast<const bf16x8*>(
            (const char*)Alds[buf] + row * 128 + ((kk * 64 + lg * 16) ^ ((row & 7) << 4)));
      }
#pragma unroll
      for (int ni = 0; ni < NF; ni++) {
        const int row = wc * (BN / 2) + ni * 16 + l15;
        bv[ni] = *reinterpret_cast<const bf16x8*>(
            (const char*)Blds[buf] + row * 128 + ((kk * 64 + lg * 16) ^ ((row & 7) << 4)));
      }
#pragma unroll
      for (int mi = 0; mi < 4; mi++)
#pragma unroll
        for (int ni = 0; ni < NF; ni++)
          acc[mi][ni] = mfma16(av[mi], bv[ni], acc[mi][ni]);
    }
  };

  if (PIPE) {
    // 2-phase: one barrier per tile; prefetch in flight across the compute.
    stage(0, 0);
    int cur = 0;
    for (int k0 = 0; k0 < Kd; k0 += 64) {
      __syncthreads();               // drains stage of buf[cur]; all waves past compute of buf[cur^1]
      if (k0 + 64 < Kd) stage(cur ^ 1, k0 + 64);
      compute(cur);
      cur ^= 1;
    }
  } else {
    for (int k0 = 0; k0 < Kd; k0 += 64) {
      stage(0, k0);
      __syncthreads();
      compute(0);
      __syncthreads();
    }
  }

#pragma unroll
  for (int mi = 0; mi < 4; mi++) {
#pragma unroll
    for (int ni = 0; ni < NF; ni++) {
      const int col = n0 + wc * (BN / 2) + ni * 16 + l15;
      const float bcol = bias[col];
#pragma unroll
      for (int r = 0; r < 4; r++) {
        const int row = m0 + wr * 64 + mi * 16 + lg * 4 + r;
        const float v = acc[mi][ni][r] + bcol;
        if (MODE == 0) {
          ((float*)Cout)[(size_t)row * N + col] = v;
        } else {
          if (col < 2048) {
            ((u16*)Cout)[(size_t)row * N + col] = f2bf(v);
          } else {
            const int bb = row >> 10, ss = row & 1023;
            Vaux[((size_t)bb * 1024 + (col - 2048)) * 1024 + ss] = f2bf(v);
          }
        }
      }
    }
  }
}

// ---------------- attention ----------------
// r17 probe: the ONE untested matrix cell -- POST-barrier batched rel loads +
// W-band combine. r8's failure was PRE-barrier issue (lost L2 priority vs the
// staging burst: +4MB HBM); r2's failure was the shuffle combine + its extra
// register pressure. Here: after __syncthreads the vmcnt queue is empty; all
// 10 rel loads issue back-to-back and their ~200cy L2 latency retires under
// the QK phase (ds_reads use lgkmcnt -- separate counter, no interference);
// the rel-MFMA phase then runs from registers. +40 VGPR live through QK only
// (~100 total < 128 cap of (256,4) -- no spill expected).
// Everything else BYTE-IDENTICAL to the 60.3us kernel (reproduced 6x).
// Revert criterion: dur > 62us or FETCH > 13.5MB -> restore r16, close session.

__global__ __launch_bounds__(256, 4) void k_attn(
    const u16* __restrict__ qkv,   // (4096, 3072): Q|K|V
    const u16* __restrict__ vt,    // (64*64, 1024): Vt[bh*64+d][s]
    const u16* __restrict__ relb,  // (1024, 64)
    u16* __restrict__ Oout)        // (4096, 1024)
{
  __shared__ u16 Klds[64 * 64];        // 8 KB, swizzled: byte = row*128 + (cb ^ ((row&7)<<4))
  __shared__ u16 Vlds[64 * 64];        // 8 KB, same swizzle (rows = d)
  __shared__ float Sbuf[4][16 * 84];   // 21 KB, per-wave: W band f32 (stride 84); P (bf16) aliases base

  const int t = threadIdx.x;
  const int lane = t & 63, w = t >> 6;
  const int l15 = lane & 15, lg = lane >> 4;
  const int blk = blockIdx.x;
  const int bh = blk & 63;             // blocks of a bh share an XCD (blk%8 == bh%8)
  // balanced q-tile mapping: groups {g, g+4, g+8, g+12} co-reside on one CU;
  // qbt per quarter j: {15-r, 8+r, 7-r, r} -> per-CU sum(nk) == 34 for all r.
  const int g = blk >> 6;
  const int jq = g >> 2, rq = g & 3;
  const int qbt = (jq == 0) ? (15 - rq) : (jq == 1) ? (8 + rq) : (jq == 2) ? (7 - rq) : rq;
  const int b = bh >> 4, h = bh & 15;
  const int qb = qbt * 64;
  const int qw = qb + w * 16;

  float* Wb = Sbuf[w];
  u16* Pb = (u16*)Sbuf[w];             // aliases Wb; ordering via wave_barrier fences

  const f32x4 fzero = {0.f, 0.f, 0.f, 0.f};

  // Q A-fragments, held in registers
  const size_t qrow = (size_t)(b * 1024 + qw + l15) * 3072 + h * 64;
  bf16x8 aQ0 = *reinterpret_cast<const bf16x8*>(qkv + qrow + lg * 8);
  bf16x8 aQ1 = *reinterpret_cast<const bf16x8*>(qkv + qrow + 32 + lg * 8);

  f32x4 oacc[4];
  float l_r[4];
#pragma unroll
  for (int r = 0; r < 4; r++) { oacc[r] = fzero; l_r[r] = 0.f; }

  // staging: thread t stages chunks t and t+256 (16B each) for K and V.
  // dest byte t*16 -> logical (row = t>>3, cb = (t&7)*16); source col byte is
  // inverse-swizzled so LDS holds the swizzled layout with a linear dest.
  const int srow = t >> 3;
  const int scb = ((t & 7) * 16) ^ ((srow & 7) << 4);
  const u16* Ks0 = qkv + (size_t)(b * 1024 + srow) * 3072 + 1024 + h * 64 + (scb >> 1);
  const u16* Ks1 = Ks0 + 32 * 3072;
  const u16* Vs0 = vt + (size_t)(bh * 64 + srow) * 1024 + (scb >> 1);
  const u16* Vs1 = Vs0 + 32 * 1024;
  u16* Kd0 = Klds + t * 8;  u16* Kd1 = Klds + (t + 256) * 8;
  u16* Vd0 = Vlds + t * 8;  u16* Vd1 = Vlds + (t + 256) * 8;

  const int nk = qbt + 1;              // uniform trip count across the 4 waves
  const float SC = 0.125f * 1.44269504f;   // fold 1/sqrt(D) and log2(e)

  for (int kt = 0; kt < nk; kt++) {
    const int k0 = kt * 64;
    gload16(Ks0 + (size_t)k0 * 3072, Kd0);
    gload16(Ks1 + (size_t)k0 * 3072, Kd1);
    gload16(Vs0 + k0, Vd0);
    gload16(Vs1 + k0, Vd1);
    __syncthreads();   // drains vmcnt for all waves; K/V tile ready; queue empty

    // rel B-fragments: batched issue into the EMPTY post-barrier vmcnt queue;
    // L2 latency retires under the QK phase below.
    const int rbase = 1008 + k0 - qw;
    bf16x8 rb0[5], rb1[5];
#pragma unroll
    for (int wj = 0; wj < 5; wj++) {
      int rr = rbase + wj * 16 + l15;
      rr = rr < 0 ? 0 : (rr > 1023 ? 1023 : rr);   // clamped rows feed only masked entries
      const u16* rp = relb + rr * 64;
      rb0[wj] = *reinterpret_cast<const bf16x8*>(rp + lg * 8);
      rb1[wj] = *reinterpret_cast<const bf16x8*>(rp + 32 + lg * 8);
    }

    // content scores: 16 q x 64 k from swizzled Klds (hides rel-load latency)
    __builtin_amdgcn_s_setprio(1);
    f32x4 sc4[4];
#pragma unroll
    for (int tt = 0; tt < 4; tt++) sc4[tt] = fzero;
#pragma unroll
    for (int tt = 0; tt < 4; tt++) {
      const int row = tt * 16 + l15;
      const int sw = (row & 7) << 4;
      bf16x8 b0 = *reinterpret_cast<const bf16x8*>((const char*)Klds + row * 128 + ((lg * 16) ^ sw));
      bf16x8 b1 = *reinterpret_cast<const bf16x8*>((const char*)Klds + row * 128 + ((64 + lg * 16) ^ sw));
      sc4[tt] = mfma16(aQ0, b0, sc4[tt]);
      sc4[tt] = mfma16(aQ1, b1, sc4[tt]);
    }

    // rel band: W[q][j] = Q[q]·rel[rbase+j], j in [0,80); MFMA from registers
#pragma unroll
    for (int wj = 0; wj < 5; wj++) {
      f32x4 z = fzero;
      z = mfma16(aQ0, rb0[wj], z);
      z = mfma16(aQ1, rb1[wj], z);
#pragma unroll
      for (int r = 0; r < 4; r++)
        Wb[(lg * 4 + r) * 84 + wj * 16 + l15] = z[r];
    }
    __builtin_amdgcn_s_setprio(0);
    __builtin_amdgcn_wave_barrier();

    // combine + mask + exp2 (defer-max: static max 0); per-lane l partials
    float pvv[4][4];
#pragma unroll
    for (int r = 0; r < 4; r++) {
      const int rowi = lg * 4 + r;
      const int q = qw + rowi;
      const float* wrow = Wb + rowi * 84 + (15 - rowi);
#pragma unroll
      for (int tt = 0; tt < 4; tt++) {
        const int kg = k0 + tt * 16 + l15;
        float s = (sc4[tt][r] + wrow[tt * 16 + l15]) * SC;
        s = (kg <= q) ? s : -1e30f;
        float p = exp2f(s);
        pvv[tt][r] = p;
        l_r[r] += p;
      }
    }
    __builtin_amdgcn_wave_barrier();
    asm volatile("" ::: "memory");     // order W-reads before aliased P-writes

    // P -> LDS bf16, swizzled rows of 128B
#pragma unroll
    for (int tt = 0; tt < 4; tt++)
#pragma unroll
      for (int r = 0; r < 4; r++) {
        const int rowi = lg * 4 + r;
        const int cb = (32 * tt + 2 * l15) ^ ((rowi & 7) << 4);
        *(u16*)((char*)Pb + rowi * 128 + cb) = f2bf(pvv[tt][r]);
      }
    __builtin_amdgcn_wave_barrier();

    // PV from swizzled Plds (A) and Vlds (B)
    __builtin_amdgcn_s_setprio(1);
#pragma unroll
    for (int s = 0; s < 2; s++) {
      const int acb = (s * 64 + lg * 16) ^ ((l15 & 7) << 4);
      bf16x8 aP = *reinterpret_cast<const bf16x8*>((const char*)Pb + l15 * 128 + acb);
#pragma unroll
      for (int dt = 0; dt < 4; dt++) {
        const int vrow = dt * 16 + l15;
        const int vcb = (s * 64 + lg * 16) ^ ((vrow & 7) << 4);
        bf16x8 bV = *reinterpret_cast<const bf16x8*>((const char*)Vlds + vrow * 128 + vcb);
        oacc[dt] = mfma16(aP, bV, oacc[dt]);
      }
    }
    __builtin_amdgcn_s_setprio(0);
    __syncthreads();   // all waves done with K/V/P before restaging
  }

  // epilogue: one row-sum reduce, scale, store
#pragma unroll
  for (int r = 0; r < 4; r++) {
    float l = l_r[r];
#pragma unroll
    for (int xm = 1; xm < 16; xm <<= 1) l += __shfl_xor(l, xm);
    const float inv = 1.f / l;
    const int q = qw + lg * 4 + r;
#pragma unroll
    for (int dt = 0; dt < 4; dt++)
      Oout[(size_t)(b * 1024 + q) * 1024 + h * 64 + dt * 16 + l15] = f2bf(oacc[dt][r] * inv);
  }
}

// ---------------- launcher ----------------

extern "C" void kernel_launch(void* const* d_in, const int* in_sizes, int n_in,
                              void* d_out, int out_size, void* d_ws, size_t ws_size,
                              hipStream_t stream) {
  const float* x   = (const float*)d_in[0];
  const float* Wq  = (const float*)d_in[1];
  const float* bq  = (const float*)d_in[2];
  const float* Wk  = (const float*)d_in[3];
  const float* bk  = (const float*)d_in[4];
  const float* Wv  = (const float*)d_in[5];
  const float* bv  = (const float*)d_in[6];
  const float* Wo  = (const float*)d_in[7];
  const float* bo  = (const float*)d_in[8];
  const float* rel = (const float*)d_in[9];

  const size_t MB = 1024 * 1024;
  char* ws = (char*)d_ws;
  u16*   xb    = (u16*)(ws);                 // 8MB; reused for attn O after QKV GEMM
  u16*   Wt    = (u16*)(ws + 8 * MB);        // 4096x1024 bf16 (Wq^T|Wk^T|Wv^T|Wo^T)
  u16*   qkvb  = (u16*)(ws + 16 * MB);       // 4096x3072 bf16 (V region unused)
  u16*   vtb   = (u16*)(ws + 40 * MB);       // 4096x1024 bf16 (transposed V)
  u16*   relbb = (u16*)(ws + 48 * MB);       // 1024x64 bf16
  float* bqkv  = (float*)(ws + 49 * MB);     // 3072 f32
  u16*   Ob    = xb;

  // 1) all conversions/packs/transposes in ONE launch (W-transpose vectorized)
  k_prep_all<<<8268, 256, 0, stream>>>(x, xb, Wq, Wk, Wv, Wo, Wt, rel, relbb, bq, bk, bv, bqkv);

  // 2) fused QKV projection (BK=64, BN=128, PIPE=0 -- proven optimum);
  //    V block written transposed into vtb
  k_gemm<2, 128, 0><<<dim3(24, 32), 256, 0, stream>>>(xb, Wt, bqkv, qkvb, vtb, 4096, 3072, 1024);

  // 3) attention: r17 probe -- post-barrier batched rel loads + W-band combine
  k_attn<<<1024, 256, 0, stream>>>(qkvb, vtb, relbb, Ob);

  // 4) output projection (BK=64, BN=64, PIPE=1 -- grid-limited so dbuf is free)
  k_gemm<0, 64, 1><<<dim3(16, 32), 256, 0, stream>>>(Ob, Wt + 3 * MB, bo, d_out, nullptr, 4096, 1024, 1024);
}